// Round 3
// baseline (646.283 us; speedup 1.0000x reference)
//
#include <hip/hip_runtime.h>
#include <hip/hip_bf16.h>
#include <hip/hip_fp16.h>

#define T_DIM 2048
#define B_DIM 32
#define LIS_DIM 1024
#define SPE_DIM 1024
#define ATT_DIM 512

typedef _Float16 f16x8 __attribute__((ext_vector_type(8)));
typedef _Float16 f16x4 __attribute__((ext_vector_type(4)));
typedef float f32x4 __attribute__((ext_vector_type(4)));

// K0: WT[c][k] f16; c<512 -> W_score[k][c], c>=512 -> W_value[k][c-512]
__global__ void transpose_w_kernel(const float* __restrict__ Ws,
                                   const float* __restrict__ Wv,
                                   _Float16* __restrict__ WT) {
  __shared__ float tile[32][33];
  int id = blockIdx.x;            // 1024 blocks
  int mat = id >> 9;
  int r = id & 511;
  int ktile = r & 31;
  int ctile = r >> 5;
  const float* W = mat ? Wv : Ws;
  int k0 = ktile * 32, c0 = ctile * 32;
  int j = threadIdx.x & 31, i0 = threadIdx.x >> 5;
  for (int i = i0; i < 32; i += 8)
    tile[i][j] = W[(size_t)(k0 + i) * ATT_DIM + c0 + j];
  __syncthreads();
  for (int i = i0; i < 32; i += 8)
    WT[(size_t)(mat * ATT_DIM + c0 + i) * LIS_DIM + k0 + j] = (_Float16)tile[j][i];
}

// K1: q[b][a] = relu(spe[b]·W_proj[:,a] + b_proj[a]), f32
__global__ void query_kernel(const float* __restrict__ spe,
                             const float* __restrict__ Wp,
                             const float* __restrict__ bp,
                             float* __restrict__ q) {
  __shared__ float s[SPE_DIM];
  int b = blockIdx.x;
  for (int i = threadIdx.x; i < SPE_DIM; i += 256) s[i] = spe[(size_t)b * SPE_DIM + i];
  __syncthreads();
  for (int a = threadIdx.x; a < ATT_DIM; a += 256) {
    float acc = bp[a];
    for (int l = 0; l < SPE_DIM; ++l)
      acc = fmaf(s[l], Wp[(size_t)l * ATT_DIM + a], acc);
    q[(size_t)b * ATT_DIM + a] = fmaxf(acc, 0.f);
  }
}

// K2: dual GEMM. One block = (b, 32 t-rows). Computes
//   scores[b][t] = q[b]·relu(x[t]@Ws + bs)   (fused epilogue)
//   vals[b][t][c] = relu(x[t]@Wv + bv) f16   (written to ws)
// Swapped MFMA orientation: mfma(W_frag, x_frag) -> lane holds (t=lo, col=hi*4+r).
__global__ __launch_bounds__(512, 4)
void dual_gemm_kernel(const float* __restrict__ x,
                      const _Float16* __restrict__ WT,
                      const float* __restrict__ bs,
                      const float* __restrict__ bv,
                      const float* __restrict__ q,
                      float* __restrict__ scores,
                      _Float16* __restrict__ vals) {
  __shared__ __align__(16) char A_lds[2][16384];  // 32 rows x 256k f16, XOR-swizzled
  __shared__ float bk_s[ATT_DIM], bv_s[ATT_DIM], q_s[ATT_DIM];
  __shared__ float red_s[32];

  const int tid = threadIdx.x;
  const int blk = blockIdx.x;
  const int b = blk & 31;
  const int t0 = (blk >> 5) << 5;   // 64 t-chunks of 32

  bk_s[tid] = bs[tid];
  bv_s[tid] = bv[tid];
  q_s[tid] = q[(size_t)b * ATT_DIM + tid];
  if (tid < 32) red_s[tid] = 0.f;

  const float* xb = x + (size_t)b * LIS_DIM;
  const int wv = tid >> 6;
  const int lane = tid & 63;
  const int lo = lane & 15;
  const int hi = lane >> 4;
  const int colBase = wv * 64;

  // stage chunk c (k in [c*256, +256)) -> buf: 32 rows x 512B, swz ^((row&7)<<4)
  auto stage = [&](int c, char* buf) {
    const int k0 = c * 256;
#pragma unroll
    for (int it = 0; it < 4; ++it) {
      int row = it * 8 + wv;
      const float4 f = ((const float4*)(xb + (size_t)(t0 + row) * (B_DIM * LIS_DIM) + k0))[lane];
      f16x4 h;
      h[0] = (_Float16)f.x; h[1] = (_Float16)f.y;
      h[2] = (_Float16)f.z; h[3] = (_Float16)f.w;
      int off = (row * 512 + lane * 8) ^ ((row & 7) << 4);
      *(f16x4*)(buf + off) = h;
    }
  };

  f32x4 kacc[2][4], vacc[2][4];
#pragma unroll
  for (int m = 0; m < 2; ++m)
#pragma unroll
    for (int n = 0; n < 4; ++n) {
      kacc[m][n] = (f32x4){0.f, 0.f, 0.f, 0.f};
      vacc[m][n] = (f32x4){0.f, 0.f, 0.f, 0.f};
    }

  const unsigned wbase = (unsigned)(colBase + lo) * LIS_DIM + hi * 8;

  stage(0, A_lds[0]);
  __syncthreads();

  for (int c = 0; c < 4; ++c) {
    if (c < 3) stage(c + 1, A_lds[(c + 1) & 1]);
    const char* buf = A_lds[c & 1];
    const int kbase = c * 256;
#pragma unroll
    for (int kk = 0; kk < 256; kk += 32) {
      f16x8 bx[2];
#pragma unroll
      for (int m = 0; m < 2; ++m) {
        int row = m * 16 + lo;
        int off = (row * 512 + kk * 2 + hi * 16) ^ ((row & 7) << 4);
        bx[m] = *(const f16x8*)(buf + off);
      }
#pragma unroll
      for (int n = 0; n < 4; ++n) {
        f16x8 wk  = *(const f16x8*)(WT + wbase + n * (16 * LIS_DIM) + kbase + kk);
        f16x8 wvv = *(const f16x8*)(WT + (ATT_DIM * LIS_DIM) + wbase + n * (16 * LIS_DIM) + kbase + kk);
        kacc[0][n] = __builtin_amdgcn_mfma_f32_16x16x32_f16(wk,  bx[0], kacc[0][n], 0, 0, 0);
        kacc[1][n] = __builtin_amdgcn_mfma_f32_16x16x32_f16(wk,  bx[1], kacc[1][n], 0, 0, 0);
        vacc[0][n] = __builtin_amdgcn_mfma_f32_16x16x32_f16(wvv, bx[0], vacc[0][n], 0, 0, 0);
        vacc[1][n] = __builtin_amdgcn_mfma_f32_16x16x32_f16(wvv, bx[1], vacc[1][n], 0, 0, 0);
      }
    }
    __syncthreads();
  }

  // vals epilogue: lane holds 4 contiguous cols per (m,n) -> 8B f16x4 stores
  _Float16* vb = vals + ((size_t)b * T_DIM + t0) * ATT_DIM;
#pragma unroll
  for (int m = 0; m < 2; ++m) {
    int t = m * 16 + lo;
#pragma unroll
    for (int n = 0; n < 4; ++n) {
      int col = colBase + n * 16 + hi * 4;
      f16x4 h;
#pragma unroll
      for (int r = 0; r < 4; ++r)
        h[r] = (_Float16)fmaxf(vacc[m][n][r] + bv_s[col + r], 0.f);
      *(f16x4*)(vb + (size_t)t * ATT_DIM + col) = h;
    }
  }

  // scores epilogue: sr[m] = sum over this lane's 16 cols, reduce over hi-groups
  float sr[2] = {0.f, 0.f};
#pragma unroll
  for (int m = 0; m < 2; ++m)
#pragma unroll
    for (int n = 0; n < 4; ++n) {
      int col = colBase + n * 16 + hi * 4;
#pragma unroll
      for (int r = 0; r < 4; ++r)
        sr[m] += q_s[col + r] * fmaxf(kacc[m][n][r] + bk_s[col + r], 0.f);
    }
#pragma unroll
  for (int m = 0; m < 2; ++m) {
    sr[m] += __shfl_xor(sr[m], 16, 64);
    sr[m] += __shfl_xor(sr[m], 32, 64);
    if (lane < 16) atomicAdd(&red_s[m * 16 + lo], sr[m]);
  }
  __syncthreads();
  if (tid < 32) scores[(size_t)b * T_DIM + t0 + tid] = red_s[tid];
}

// K3: masked softmax per b; writes attn f32 to out, zeroes context region of out
__global__ void softmax_kernel(const float* __restrict__ scores,
                               const int* __restrict__ llen,
                               float* __restrict__ attn_out,   // d_out + 16384
                               float* __restrict__ ctx_out) {  // d_out (zeroed here)
  __shared__ float rmax[4], rsum[4];
  int b = blockIdx.x, tid = threadIdx.x;
  int L = llen[b];
  float v[8];
  float mx = -1e30f;
  for (int i = 0; i < 8; ++i) {
    int t = i * 256 + tid;
    float s = scores[(size_t)b * T_DIM + t];
    if (t >= L) s -= 100.f;
    v[i] = s;
    mx = fmaxf(mx, s);
  }
  for (int d = 1; d < 64; d <<= 1) mx = fmaxf(mx, __shfl_xor(mx, d, 64));
  if ((tid & 63) == 0) rmax[tid >> 6] = mx;
  __syncthreads();
  mx = fmaxf(fmaxf(rmax[0], rmax[1]), fmaxf(rmax[2], rmax[3]));
  float sum = 0.f;
  for (int i = 0; i < 8; ++i) { v[i] = expf(v[i] - mx); sum += v[i]; }
  for (int d = 1; d < 64; d <<= 1) sum += __shfl_xor(sum, d, 64);
  if ((tid & 63) == 0) rsum[tid >> 6] = sum;
  __syncthreads();
  sum = rsum[0] + rsum[1] + rsum[2] + rsum[3];
  float inv = 1.f / sum;
  for (int i = 0; i < 8; ++i) {
    int t = i * 256 + tid;
    attn_out[(size_t)b * T_DIM + t] = v[i] * inv;
  }
  for (int i = tid; i < ATT_DIM; i += 256) ctx_out[(size_t)b * ATT_DIM + i] = 0.f;
}

// K4: ctx[b][a] = sum_t attn[b][t] * vals[b][t][a]; 8 t-chunks per b, atomics
__global__ __launch_bounds__(512)
void ctx_kernel(const _Float16* __restrict__ vals,
                const float* __restrict__ attn,
                float* __restrict__ ctx) {
  __shared__ float attn_s[256];
  __shared__ float red[ATT_DIM];
  int tid = threadIdx.x, blk = blockIdx.x;
  int b = blk >> 3, tb = (blk & 7) * 256;
  if (tid < 256) attn_s[tid] = attn[(size_t)b * T_DIM + tb + tid];
  red[tid] = 0.f;
  __syncthreads();
  int wv = tid >> 6, lane = tid & 63, a0 = lane * 8;
  const _Float16* vp = vals + ((size_t)b * T_DIM + tb + wv * 32) * ATT_DIM + a0;
  float acc[8] = {};
  for (int r = 0; r < 32; ++r) {
    f16x8 v = *(const f16x8*)(vp + (size_t)r * ATT_DIM);
    float w = attn_s[wv * 32 + r];
#pragma unroll
    for (int j = 0; j < 8; ++j) acc[j] += w * (float)v[j];
  }
#pragma unroll
  for (int j = 0; j < 8; ++j) atomicAdd(&red[a0 + j], acc[j]);
  __syncthreads();
  atomicAdd(&ctx[(size_t)b * ATT_DIM + tid], red[tid]);
}

extern "C" void kernel_launch(void* const* d_in, const int* in_sizes, int n_in,
                              void* d_out, int out_size, void* d_ws, size_t ws_size,
                              hipStream_t stream) {
  const float* x   = (const float*)d_in[0];
  const float* spe = (const float*)d_in[1];
  const int*   len = (const int*)d_in[2];
  const float* Ws  = (const float*)d_in[4];
  const float* bs  = (const float*)d_in[5];
  const float* Wv  = (const float*)d_in[6];
  const float* bv  = (const float*)d_in[7];
  const float* Wp  = (const float*)d_in[8];
  const float* bp  = (const float*)d_in[9];
  float* out = (float*)d_out;  // [0,16384): context f32, [16384,81920): attn f32

  char* ws = (char*)d_ws;
  _Float16* WT  = (_Float16*)ws;                             // 2 MB
  float* q      = (float*)(ws + (2u << 20));                 // 64 KB
  float* scores = (float*)(ws + (2u << 20) + (64u << 10));   // 256 KB
  _Float16* vals = (_Float16*)(ws + (4u << 20));             // 64 MB f16 [32][2048][512]

  transpose_w_kernel<<<dim3(1024), dim3(256), 0, stream>>>(Ws, Wv, WT);
  query_kernel<<<dim3(32), dim3(256), 0, stream>>>(spe, Wp, bp, q);
  dual_gemm_kernel<<<dim3(2048), dim3(512), 0, stream>>>(x, WT, bs, bv, q, scores, vals);
  softmax_kernel<<<dim3(32), dim3(256), 0, stream>>>(scores, len, out + 16384, out);
  ctx_kernel<<<dim3(256), dim3(512), 0, stream>>>(vals, out + 16384, out);
}

// Round 4
// 299.413 us; speedup vs baseline: 2.1585x; 2.1585x over previous
//
#include <hip/hip_runtime.h>
#include <hip/hip_bf16.h>
#include <hip/hip_fp16.h>

#define T_DIM 2048
#define B_DIM 32
#define LIS_DIM 1024
#define SPE_DIM 1024
#define ATT_DIM 512

typedef _Float16 f16x8 __attribute__((ext_vector_type(8)));
typedef _Float16 f16x4 __attribute__((ext_vector_type(4)));
typedef float f32x4 __attribute__((ext_vector_type(4)));

// K0: pack W into MFMA-fragment order:
// WTf_f16x8[((mat*32+ct)*32+ks)*64 + lane] : h[j] = W[ks*32+hi*8+j][ct*16+lo]
// -> a wave's B-fragment load is 1KB contiguous.
__global__ void transpose_w_kernel(const float* __restrict__ Ws,
                                   const float* __restrict__ Wv,
                                   _Float16* __restrict__ WTf) {
  __shared__ float t17[1024 * 17];  // [k][c], stride 17 (conflict-free)
  int blk = blockIdx.x;             // 64 = mat(2) x ct(32)
  int mat = blk >> 5, ct = blk & 31;
  int tid = threadIdx.x;
  const float* W = mat ? Wv : Ws;
  for (int e = tid; e < 16384; e += 256) {
    int k = e >> 4, c = e & 15;
    t17[k * 17 + c] = W[(size_t)k * ATT_DIM + ct * 16 + c];
  }
  __syncthreads();
  int wv4 = tid >> 6, lane = tid & 63, lo = lane & 15, hi = lane >> 4;
  for (int ks = wv4; ks < 32; ks += 4) {
    f16x8 h;
#pragma unroll
    for (int j = 0; j < 8; ++j)
      h[j] = (_Float16)t17[(ks * 32 + hi * 8 + j) * 17 + lo];
    ((f16x8*)WTf)[((size_t)((mat * 32 + ct) * 32 + ks)) * 64 + lane] = h;
  }
}

// K1: q[b][a] = relu(spe[b]·W_proj[:,a] + b_proj[a]), f32
__global__ void query_kernel(const float* __restrict__ spe,
                             const float* __restrict__ Wp,
                             const float* __restrict__ bp,
                             float* __restrict__ q) {
  __shared__ float s[SPE_DIM];
  int b = blockIdx.x;
  for (int i = threadIdx.x; i < SPE_DIM; i += 256) s[i] = spe[(size_t)b * SPE_DIM + i];
  __syncthreads();
  for (int a = threadIdx.x; a < ATT_DIM; a += 256) {
    float acc = bp[a];
    for (int l = 0; l < SPE_DIM; ++l)
      acc = fmaf(s[l], Wp[(size_t)l * ATT_DIM + a], acc);
    q[(size_t)b * ATT_DIM + a] = fmaxf(acc, 0.f);
  }
}

// K2: dual GEMM, M=64 rows (one b, 64 t's). Swapped orientation mfma(W, x).
// scores fused; vals written packed (lane-natural, fully coalesced).
__global__ __launch_bounds__(512)
void dual_gemm_kernel(const float* __restrict__ x,
                      const _Float16* __restrict__ WTf,
                      const float* __restrict__ bs,
                      const float* __restrict__ bv,
                      const float* __restrict__ q,
                      float* __restrict__ scores,
                      _Float16* __restrict__ vals_p) {
  __shared__ __align__(16) char A_lds[2][16384];  // 64 rows x 128k f16, XOR swz
  __shared__ float bk_s[ATT_DIM], bv_s[ATT_DIM], q_s[ATT_DIM];
  __shared__ float red_s[64];

  const int tid = threadIdx.x;
  const int blk = blockIdx.x;
  const int b = blk & 31;
  const int tc = blk >> 5;          // 32 chunks of 64 t
  const int t0 = tc * 64;

  bk_s[tid] = bs[tid];
  bv_s[tid] = bv[tid];
  q_s[tid] = q[(size_t)b * ATT_DIM + tid];
  if (tid < 64) red_s[tid] = 0.f;

  const float* xb = x + (size_t)b * LIS_DIM;
  const int wv = tid >> 6;
  const int lane = tid & 63;
  const int lo = lane & 15;
  const int hi = lane >> 4;

  // stage chunk c (k in [c*128,+128)) -> 64 rows x 256B, swz ^((row&7)<<4)
  auto stage = [&](int c, char* buf) {
    const int k0 = c * 128;
#pragma unroll
    for (int it = 0; it < 4; ++it) {
      int idx = it * 512 + tid;     // 2048 float4 = 64 rows x 32 float4
      int row = idx >> 5;
      int c4 = idx & 31;
      const float4 f =
          ((const float4*)(xb + (size_t)(t0 + row) * (B_DIM * LIS_DIM) + k0))[c4];
      f16x4 h;
      h[0] = (_Float16)f.x; h[1] = (_Float16)f.y;
      h[2] = (_Float16)f.z; h[3] = (_Float16)f.w;
      int off = (row * 256 + c4 * 8) ^ ((row & 7) << 4);
      *(f16x4*)(buf + off) = h;
    }
  };

  f32x4 kacc[4][4], vacc[4][4];
#pragma unroll
  for (int m = 0; m < 4; ++m)
#pragma unroll
    for (int n = 0; n < 4; ++n) {
      kacc[m][n] = (f32x4){0.f, 0.f, 0.f, 0.f};
      vacc[m][n] = (f32x4){0.f, 0.f, 0.f, 0.f};
    }

  stage(0, A_lds[0]);
  __syncthreads();

  const f16x8* Wf = (const f16x8*)WTf;

  for (int c = 0; c < 8; ++c) {
    if (c < 7) stage(c + 1, A_lds[(c + 1) & 1]);
    const char* buf = A_lds[c & 1];
#pragma unroll
    for (int kki = 0; kki < 4; ++kki) {
      const int kk = kki * 32;
      const int ks = c * 4 + kki;
      f16x8 bx[4];
#pragma unroll
      for (int m = 0; m < 4; ++m) {
        int row = m * 16 + lo;
        int off = (row * 256 + kk * 2 + hi * 16) ^ ((row & 7) << 4);
        bx[m] = *(const f16x8*)(buf + off);
      }
#pragma unroll
      for (int n = 0; n < 4; ++n) {
        int ct = wv * 4 + n;
        f16x8 wk  = Wf[(size_t)(ct * 32 + ks) * 64 + lane];
        f16x8 wvv = Wf[(size_t)((32 + ct) * 32 + ks) * 64 + lane];
#pragma unroll
        for (int m = 0; m < 4; ++m) {
          kacc[m][n] = __builtin_amdgcn_mfma_f32_16x16x32_f16(wk,  bx[m], kacc[m][n], 0, 0, 0);
          vacc[m][n] = __builtin_amdgcn_mfma_f32_16x16x32_f16(wvv, bx[m], vacc[m][n], 0, 0, 0);
        }
      }
    }
    __syncthreads();
  }

  // vals epilogue: packed lane-natural layout, 512B contiguous per (m,n) store
  // vals_p element: [((b*32+tc)*8+wv)*16 + m*4 + n]*256 + lane*4 (f16 units)
  _Float16* vp = vals_p + ((size_t)(b * 32 + tc) * 8 + wv) * 4096;
#pragma unroll
  for (int m = 0; m < 4; ++m)
#pragma unroll
    for (int n = 0; n < 4; ++n) {
      int col = wv * 64 + n * 16 + hi * 4;
      f16x4 h;
#pragma unroll
      for (int r = 0; r < 4; ++r)
        h[r] = (_Float16)fmaxf(vacc[m][n][r] + bv_s[col + r], 0.f);
      *(f16x4*)(vp + (m * 4 + n) * 256 + lane * 4) = h;
    }

  // scores epilogue
  float sr[4] = {0.f, 0.f, 0.f, 0.f};
#pragma unroll
  for (int m = 0; m < 4; ++m)
#pragma unroll
    for (int n = 0; n < 4; ++n) {
      int col = wv * 64 + n * 16 + hi * 4;
#pragma unroll
      for (int r = 0; r < 4; ++r)
        sr[m] += q_s[col + r] * fmaxf(kacc[m][n][r] + bk_s[col + r], 0.f);
    }
#pragma unroll
  for (int m = 0; m < 4; ++m) {
    sr[m] += __shfl_xor(sr[m], 16, 64);
    sr[m] += __shfl_xor(sr[m], 32, 64);
    if (lane < 16) atomicAdd(&red_s[m * 16 + lo], sr[m]);
  }
  __syncthreads();
  if (tid < 64) scores[(size_t)b * T_DIM + t0 + tid] = red_s[tid];
}

// K3: masked softmax per b; writes attn f32 to out, zeroes context region of out
__global__ void softmax_kernel(const float* __restrict__ scores,
                               const int* __restrict__ llen,
                               float* __restrict__ attn_out,   // d_out + 16384
                               float* __restrict__ ctx_out) {  // d_out (zeroed here)
  __shared__ float rmax[4], rsum[4];
  int b = blockIdx.x, tid = threadIdx.x;
  int L = llen[b];
  float v[8];
  float mx = -1e30f;
  for (int i = 0; i < 8; ++i) {
    int t = i * 256 + tid;
    float s = scores[(size_t)b * T_DIM + t];
    if (t >= L) s -= 100.f;
    v[i] = s;
    mx = fmaxf(mx, s);
  }
  for (int d = 1; d < 64; d <<= 1) mx = fmaxf(mx, __shfl_xor(mx, d, 64));
  if ((tid & 63) == 0) rmax[tid >> 6] = mx;
  __syncthreads();
  mx = fmaxf(fmaxf(rmax[0], rmax[1]), fmaxf(rmax[2], rmax[3]));
  float sum = 0.f;
  for (int i = 0; i < 8; ++i) { v[i] = expf(v[i] - mx); sum += v[i]; }
  for (int d = 1; d < 64; d <<= 1) sum += __shfl_xor(sum, d, 64);
  if ((tid & 63) == 0) rsum[tid >> 6] = sum;
  __syncthreads();
  sum = rsum[0] + rsum[1] + rsum[2] + rsum[3];
  float inv = 1.f / sum;
  for (int i = 0; i < 8; ++i) {
    int t = i * 256 + tid;
    attn_out[(size_t)b * T_DIM + t] = v[i] * inv;
  }
  for (int i = tid; i < ATT_DIM; i += 256) ctx_out[(size_t)b * ATT_DIM + i] = 0.f;
}

// K4: ctx[b][col] = sum_t attn[b][t] * vals[t][col], decoding packed layout.
// grid 128 = b(32) x tcg(4); each block does 8 tc-chunks (512 t).
__global__ __launch_bounds__(512)
void ctx_kernel(const _Float16* __restrict__ vals_p,
                const float* __restrict__ attn,
                float* __restrict__ ctx) {
  __shared__ float attn_s[512];
  int blk = blockIdx.x;
  int b = blk >> 2, tcg = blk & 3;
  int tid = threadIdx.x;
  int wv = tid >> 6, lane = tid & 63, lo = lane & 15, hi = lane >> 4;
  attn_s[tid] = attn[(size_t)b * T_DIM + tcg * 512 + tid];
  __syncthreads();
  float cacc[4][4] = {};
  for (int i = 0; i < 8; ++i) {
    int tc = tcg * 8 + i;
    const _Float16* vp = vals_p + ((size_t)(b * 32 + tc) * 8 + wv) * 4096;
#pragma unroll
    for (int m = 0; m < 4; ++m) {
      float w = attn_s[i * 64 + m * 16 + lo];
#pragma unroll
      for (int n = 0; n < 4; ++n) {
        f16x4 v = *(const f16x4*)(vp + (m * 4 + n) * 256 + lane * 4);
#pragma unroll
        for (int r = 0; r < 4; ++r) cacc[n][r] += w * (float)v[r];
      }
    }
  }
#pragma unroll
  for (int n = 0; n < 4; ++n)
#pragma unroll
    for (int r = 0; r < 4; ++r) {
      float v = cacc[n][r];
      v += __shfl_xor(v, 1, 64);
      v += __shfl_xor(v, 2, 64);
      v += __shfl_xor(v, 4, 64);
      v += __shfl_xor(v, 8, 64);
      if (lo == 0)
        atomicAdd(&ctx[(size_t)b * ATT_DIM + wv * 64 + n * 16 + hi * 4 + r], v);
    }
}

extern "C" void kernel_launch(void* const* d_in, const int* in_sizes, int n_in,
                              void* d_out, int out_size, void* d_ws, size_t ws_size,
                              hipStream_t stream) {
  const float* x   = (const float*)d_in[0];
  const float* spe = (const float*)d_in[1];
  const int*   len = (const int*)d_in[2];
  const float* Ws  = (const float*)d_in[4];
  const float* bs  = (const float*)d_in[5];
  const float* Wv  = (const float*)d_in[6];
  const float* bv  = (const float*)d_in[7];
  const float* Wp  = (const float*)d_in[8];
  const float* bp  = (const float*)d_in[9];
  float* out = (float*)d_out;  // [0,16384): context f32, [16384,81920): attn f32

  char* ws = (char*)d_ws;
  _Float16* WTf  = (_Float16*)ws;                            // 2 MB packed frags
  float* q       = (float*)(ws + (2u << 20));                // 64 KB
  float* scores  = (float*)(ws + (2u << 20) + (64u << 10));  // 256 KB
  _Float16* vals = (_Float16*)(ws + (4u << 20));             // 64 MB packed

  transpose_w_kernel<<<dim3(64), dim3(256), 0, stream>>>(Ws, Wv, WTf);
  query_kernel<<<dim3(32), dim3(256), 0, stream>>>(spe, Wp, bp, q);
  dual_gemm_kernel<<<dim3(1024), dim3(512), 0, stream>>>(x, WTf, bs, bv, q, scores, vals);
  softmax_kernel<<<dim3(32), dim3(256), 0, stream>>>(scores, len, out + 16384, out);
  ctx_kernel<<<dim3(128), dim3(512), 0, stream>>>(vals, out + 16384, out);
}